// Round 7
// baseline (39968.927 us; speedup 1.0000x reference)
//
#include <hip/hip_runtime.h>
#include <hip/hip_bf16.h>
#include <math.h>

// PRNN round 7: zero-split-K column-stationary persistent kernel.
// Key insight: recurrence is row(batch)-independent; exchange is columns only.
// 256 WGs = 2 row-halves x 128 col-groups. Each WG: output [128 rows x 16 cols],
// FULL composite K = 2560 ([h | x_t]); weights (16 cols x 2560) LDS-resident 80KB.
// Gate applied in-register (f32 master state in VGPRs). NO partial exchange.
// One rendezvous/step: WG polls its half's 128 flags. Decoder lagged 2 steps,
// off critical path (row-half-aligned tiles preserve release/acquire transitivity).
// y_t = h_t@Wdec^T + b_dec ; h_t = (1-s)h_{t-1} + s*a*tanh(x_t@Wenc^T + b_enc + h_{t-1}@Wrec^T + b_rec)

#define B_   256
#define T_   512
#define NI_  512
#define NH_  2048
#define NO_  256
#define NCH  40        // composite-K chunks of 64 (32 h-chunks + 8 x-chunks)

typedef __bf16 bf16_t;
typedef __bf16 bf16x8 __attribute__((ext_vector_type(8)));
typedef float  f32x4  __attribute__((ext_vector_type(4)));

#define MFMA16(a,b,c) __builtin_amdgcn_mfma_f32_16x16x32_bf16((a),(b),(c),0,0,0)

__device__ __forceinline__ void nt_store_f(float v, float* p) {
  __builtin_nontemporal_store(v, p);
}
__device__ __forceinline__ void nt_store_v4(f32x4 v, float* p) {
  __builtin_nontemporal_store(v, reinterpret_cast<f32x4*>(p));
}

__global__ __launch_bounds__(256) void k_cvt(const float* __restrict__ src,
                                             bf16_t* __restrict__ dst, int n) {
  int i = blockIdx.x * 256 + threadIdx.x;
  const int stride = gridDim.x * 256;
  for (; i < n; i += stride) dst[i] = (bf16_t)src[i];
}

// One 16x16 tile of y = h @ Wdec^T + b_dec per WG (K=2048 split over 4 waves).
// Tile rows (bid>>4)*16 lie inside row-half (bid>>7) — same half as the WG's
// recurrent work, so the phase-A acquire chain covers dec's h reads.
__device__ __forceinline__ void dec_tile(int wgid, int tid,
    const bf16_t* __restrict__ hbp, const bf16_t* __restrict__ Wdec,
    const float* __restrict__ b_dec, float* __restrict__ y_out, float* Ds) {
  const int lane = tid & 63;
  const int wv2 = tid >> 6;
  const int fl = lane & 15;
  const int kg = lane >> 4;
  const int dr = (wgid >> 4) * 16;
  const int dc = (wgid & 15) * 16;
  f32x4 dacc = {0.f, 0.f, 0.f, 0.f};
  const int kw = wv2 * 512;
  #pragma unroll 4
  for (int ks = 0; ks < 16; ++ks) {
    const int k = kw + ks * 32 + kg * 8;
    bf16x8 af = *reinterpret_cast<const bf16x8*>(hbp + (size_t)(dr + fl) * NH_ + k);
    bf16x8 bf = *reinterpret_cast<const bf16x8*>(Wdec + (size_t)(dc + fl) * NH_ + k);
    dacc = MFMA16(af, bf, dacc);
  }
  __syncthreads();
  #pragma unroll
  for (int j = 0; j < 4; ++j)
    Ds[wv2 * 256 + (kg * 4 + j) * 16 + fl] = dacc[j];
  __syncthreads();
  const int er = tid >> 4, ec = tid & 15;
  const float yv = Ds[er * 16 + ec] + Ds[256 + er * 16 + ec] + Ds[512 + er * 16 + ec] +
                   Ds[768 + er * 16 + ec] + b_dec[dc + ec];
  nt_store_f(yv, &y_out[(size_t)(dr + er) * NO_ + (dc + ec)]);
}

__global__ __launch_bounds__(256, 1) void k_prnn(
    const float* __restrict__ x,
    const float* __restrict__ dt_p, const float* __restrict__ a_p,
    const float* __restrict__ Wrec, const float* __restrict__ Wenc,
    const bf16_t* __restrict__ Wdec,
    const float* __restrict__ b_rec, const float* __restrict__ b_enc,
    const float* __restrict__ b_dec,
    bf16_t* __restrict__ hb,          // 4 ring slots of [B, NH] bf16 (NT-written)
    bf16_t* __restrict__ xb,          // 2 ring slots of [B, NI] bf16
    int* __restrict__ flags,          // 256 flags, 64B-strided
    float* __restrict__ out)
{
  __shared__ alignas(16) bf16x8 Wl[16 * 320];     // 80KB: 16 cols x 320 granules
  __shared__ alignas(16) bf16x8 Abuf[2][1024];    // 32KB: 2 x (128 rows x 8 granules)
  __shared__ alignas(16) float  Hs[128 * 20];     // 10KB: gate transpose / dec scratch

  const int tid  = threadIdx.x;
  const int lane = tid & 63;
  const int fl   = lane & 15;
  const int kg   = lane >> 4;
  const int bid  = blockIdx.x;
  const int ch   = bid >> 7;          // row half (0/1)
  const int cg   = bid & 127;         // col group (16 cols)
  const int rbase = ch * 128;
  const int r2 = tid >> 1;            // staging row 0..127
  const int c2 = tid & 1;             // staging K-half

  const float sgate = 1.f / (1.f + expf(-dt_p[0]));
  const float av = a_p[0];
  const float gi = 1.f - sgate;
  const float sav = sgate * av;
  const int col_g = cg * 16 + fl;     // this lane's output column
  const float bias = b_rec[col_g] + b_enc[col_g];

  // f32 master state: hr[rt*4+j] = h[rbase + rt*16 + kg*4 + j][col_g]
  float hr[32];
  #pragma unroll
  for (int i = 0; i < 32; ++i) hr[i] = 0.f;

  // ---- prologue 1: W slice (16 cols x composite K 2560) -> LDS, bf16, swizzled
  {
    const int c = tid & 15;           // local col
    const int part = tid >> 4;        // 16 threads per col
    const int c_g = cg * 16 + c;
    #pragma unroll 4
    for (int i = 0; i < 20; ++i) {
      const int g = part * 20 + i;    // granule 0..319
      const int k = g * 8;
      const float* src = (k < NH_) ? (Wrec + (size_t)c_g * NH_ + k)
                                   : (Wenc + (size_t)c_g * NI_ + (k - NH_));
      float4 f0 = reinterpret_cast<const float4*>(src)[0];
      float4 f1 = reinterpret_cast<const float4*>(src)[1];
      bf16x8 w8 = {(bf16_t)f0.x, (bf16_t)f0.y, (bf16_t)f0.z, (bf16_t)f0.w,
                   (bf16_t)f1.x, (bf16_t)f1.y, (bf16_t)f1.z, (bf16_t)f1.w};
      Wl[c * 320 + (g ^ (c & 7))] = w8;
    }
  }
  // ---- prologue 2: convert own share of x_0 (rows of my half, cols cg*4..+4)
  {
    const int r = tid & 127, cp = tid >> 7;
    const float* xs = x + ((size_t)(rbase + r) * T_ + 0) * NI_ + cg * 4 + cp * 2;
    union { unsigned u; bf16_t h[2]; } pk;
    pk.h[0] = (bf16_t)xs[0]; pk.h[1] = (bf16_t)xs[1];
    __builtin_nontemporal_store(pk.u,
        reinterpret_cast<unsigned*>(xb + (size_t)(rbase + r) * NI_ + cg * 4 + cp * 2));
  }
  __syncthreads();                    // drain stores (per-wave vmcnt)
  if (tid == 0)
    __hip_atomic_fetch_add(flags + bid * 16, 1, __ATOMIC_RELEASE, __HIP_MEMORY_SCOPE_AGENT);

  #pragma unroll 1
  for (int t = 0; t < T_; ++t) {
    const bf16_t* hb_in  = hb + (size_t)(t & 3) * B_ * NH_;
    bf16_t*       hb_out = hb + (size_t)((t + 1) & 3) * B_ * NH_;
    const bf16_t* xb_in  = xb + (size_t)(t & 1) * B_ * NI_;

    // ---- phase A: poll my half's 128 flags >= t+1 (parallel, 1 per thread)
    if (tid < 128) {
      int* p = flags + (ch * 128 + tid) * 16;
      while (__hip_atomic_load(p, __ATOMIC_RELAXED, __HIP_MEMORY_SCOPE_AGENT) < t + 1)
        __builtin_amdgcn_s_sleep(2);
    }
    __syncthreads();
    if (tid == 0)
      (void)__hip_atomic_load(flags, __ATOMIC_ACQUIRE, __HIP_MEMORY_SCOPE_AGENT);
    __syncthreads();

    // ---- phase B: GEMM [128 x 16] over composite K=2560, reg-prefetch depth 3
    f32x4 acc[8];
    #pragma unroll
    for (int i = 0; i < 8; ++i) acc[i] = f32x4{0.f, 0.f, 0.f, 0.f};

    bf16x8 sbuf[3][4];
    auto issue = [&](int c, bf16x8* dst) {
      const bf16_t* srow;
      if (c < 32) srow = hb_in + (size_t)(rbase + r2) * NH_ + c * 64;
      else        srow = xb_in + (size_t)(rbase + r2) * NI_ + (c - 32) * 64;
      const bf16x8* s8 = reinterpret_cast<const bf16x8*>(srow) + c2 * 4;
      dst[0] = s8[0]; dst[1] = s8[1]; dst[2] = s8[2]; dst[3] = s8[3];
    };
    issue(0, sbuf[0]); issue(1, sbuf[1]); issue(2, sbuf[2]);

    #pragma unroll 1
    for (int c = 0; c < NCH; ++c) {
      bf16x8* Ab = Abuf[c & 1];
      __syncthreads();                 // all waves done reading this slot (c-2)
      {
        bf16x8* sb = sbuf[c % 3];
        #pragma unroll
        for (int i = 0; i < 4; ++i)
          Ab[r2 * 8 + ((c2 * 4 + i) ^ (r2 & 7))] = sb[i];
      }
      __syncthreads();
      if (c + 3 < NCH) issue(c + 3, sbuf[c % 3]);   // refill freed buffer
      #pragma unroll
      for (int ks = 0; ks < 2; ++ks) {
        const int gA = ks * 4 + kg;
        bf16x8 b = Wl[fl * 320 + ((c * 8 + gA) ^ (fl & 7))];
        #pragma unroll
        for (int rt = 0; rt < 8; ++rt) {
          const int row = rt * 16 + fl;
          bf16x8 a = Ab[row * 8 + (gA ^ (row & 7))];
          acc[rt] = MFMA16(a, b, acc[rt]);
        }
      }
    }

    // ---- phase C: gate in-register, stage to Hs (stride-20 f32, 16B-aligned rows)
    #pragma unroll
    for (int rt = 0; rt < 8; ++rt)
      #pragma unroll
      for (int j = 0; j < 4; ++j) {
        const float o = gi * hr[rt * 4 + j] + sav * tanhf(acc[rt][j] + bias);
        hr[rt * 4 + j] = o;
        Hs[(rt * 16 + kg * 4 + j) * 20 + fl] = o;
      }
    __syncthreads();
    {
      const int c8 = c2 * 8;
      f32x4 u = *reinterpret_cast<f32x4*>(&Hs[r2 * 20 + c8]);
      f32x4 w = *reinterpret_cast<f32x4*>(&Hs[r2 * 20 + c8 + 4]);
      bf16x8 ob = {(bf16_t)u[0], (bf16_t)u[1], (bf16_t)u[2], (bf16_t)u[3],
                   (bf16_t)w[0], (bf16_t)w[1], (bf16_t)w[2], (bf16_t)w[3]};
      f32x4 obv;
      __builtin_memcpy(&obv, &ob, 16);
      nt_store_v4(obv, reinterpret_cast<float*>(
          hb_out + (size_t)(rbase + r2) * NH_ + cg * 16 + c8));
      if (t == T_ - 1) {   // exact f32 final h from register master (via Hs)
        float* hd = out + (size_t)T_ * B_ * NO_ + (size_t)(rbase + r2) * NH_ + cg * 16 + c8;
        nt_store_v4(u, hd);
        nt_store_v4(w, hd + 4);
      }
    }
    // ---- convert own share of x_{t+1}
    if (t + 1 < T_) {
      const int r = tid & 127, cp = tid >> 7;
      const float* xs = x + ((size_t)(rbase + r) * T_ + (t + 1)) * NI_ + cg * 4 + cp * 2;
      union { unsigned u; bf16_t h[2]; } pk;
      pk.h[0] = (bf16_t)xs[0]; pk.h[1] = (bf16_t)xs[1];
      __builtin_nontemporal_store(pk.u, reinterpret_cast<unsigned*>(
          xb + (size_t)((t + 1) & 1) * B_ * NI_ + (size_t)(rbase + r) * NI_ + cg * 4 + cp * 2));
    }
    __syncthreads();                   // drain all stores
    if (tid == 0)
      __hip_atomic_fetch_add(flags + bid * 16, 1, __ATOMIC_RELEASE, __HIP_MEMORY_SCOPE_AGENT);

    // ---- phase E (off critical path): decoder y_{t-2} from hb slot (t-1)&3.
    // Covered by phase-A acquire chain (tile rows within own half); slot reused
    // only at step t+2's gate, which transitively follows my release(t+1).
    if (t >= 2)
      dec_tile(bid, tid, hb + (size_t)((t - 1) & 3) * B_ * NH_, Wdec, b_dec,
               out + (size_t)(t - 2) * B_ * NO_, Hs);
  }

  // ---- epilogue: y_{T-2} (slot (T-1)&3) and y_{T-1} (slot T&3 = 0)
  if (tid < 128) {
    int* p = flags + (ch * 128 + tid) * 16;
    while (__hip_atomic_load(p, __ATOMIC_RELAXED, __HIP_MEMORY_SCOPE_AGENT) < T_)
      __builtin_amdgcn_s_sleep(2);
  }
  __syncthreads();
  if (tid == 0)
    (void)__hip_atomic_load(flags, __ATOMIC_ACQUIRE, __HIP_MEMORY_SCOPE_AGENT);
  __syncthreads();
  dec_tile(bid, tid, hb + (size_t)((T_ - 1) & 3) * B_ * NH_, Wdec, b_dec,
           out + (size_t)(T_ - 2) * B_ * NO_, Hs);
  if (tid < 128) {
    int* p = flags + (ch * 128 + tid) * 16;
    while (__hip_atomic_load(p, __ATOMIC_RELAXED, __HIP_MEMORY_SCOPE_AGENT) < T_ + 1)
      __builtin_amdgcn_s_sleep(2);
  }
  __syncthreads();
  if (tid == 0)
    (void)__hip_atomic_load(flags, __ATOMIC_ACQUIRE, __HIP_MEMORY_SCOPE_AGENT);
  __syncthreads();
  dec_tile(bid, tid, hb /* slot 0 = S_{T-1} */, Wdec, b_dec,
           out + (size_t)(T_ - 1) * B_ * NO_, Hs);
}

extern "C" void kernel_launch(void* const* d_in, const int* in_sizes, int n_in,
                              void* d_out, int out_size, void* d_ws, size_t ws_size,
                              hipStream_t stream) {
  const float* x     = (const float*)d_in[0];
  const float* dt_p  = (const float*)d_in[1];
  const float* a_p   = (const float*)d_in[2];
  const float* W_enc = (const float*)d_in[3];
  const float* b_enc = (const float*)d_in[4];
  const float* W_rec = (const float*)d_in[5];
  const float* b_rec = (const float*)d_in[6];
  const float* W_dec = (const float*)d_in[7];
  const float* b_dec = (const float*)d_in[8];
  float* out = (float*)d_out;

  char* p = (char*)d_ws;
  bf16_t* hb     = (bf16_t*)p;  p += 4 * (size_t)B_ * NH_ * 2;   // 4MB (ring of 4)
  bf16_t* xb     = (bf16_t*)p;  p += 2 * (size_t)B_ * NI_ * 2;   // 512KB (ring of 2)
  bf16_t* Wdec_b = (bf16_t*)p;  p += (size_t)NO_ * NH_ * 2;      // 1MB
  int*    flags  = (int*)p;     p += 256 * 16 * 4;               // 16KB

  hipMemsetAsync(hb, 0, (size_t)B_ * NH_ * 2, stream);   // slot 0 = S_{-1} = 0
  hipMemsetAsync(flags, 0, 256 * 16 * 4, stream);

  k_cvt<<<64, 256, 0, stream>>>(W_dec, Wdec_b, NO_ * NH_);

  k_prnn<<<dim3(256), dim3(256), 0, stream>>>(
      x, dt_p, a_p, W_rec, W_enc, Wdec_b, b_rec, b_enc, b_dec,
      hb, xb, flags, out);
}

// Round 8
// 16355.647 us; speedup vs baseline: 2.4437x; 2.4437x over previous
//
#include <hip/hip_runtime.h>
#include <hip/hip_bf16.h>
#include <math.h>

// PRNN round 8: wide-WG column-stationary persistent kernel, zero split-K.
// 256 WGs x 1024 threads (16 waves). WG (ch, cg): rows = half ch (128), cols =
// cg*16..+16, FULL composite K=2560 ([h|x_t]). Weights 80KB LDS. No LDS A-staging,
// no K-loop barriers: waves MFMA from global-loaded fragments (h L2-amplified per
// XCD after acquire-inv). K split 2-way across wave pairs, LDS-reduced. Gate in
// register (f32 master state). One rendezvous/step (128 flags, paced poll).
// Decoder lagged 2 steps, off critical path. Ring/flag protocol identical to r7.
// y_t = h_t@Wdec^T + b_dec ; h_t = (1-s)h_{t-1} + s*a*tanh(x_t@Wenc^T + b_enc + h_{t-1}@Wrec^T + b_rec)

#define B_   256
#define T_   512
#define NI_  512
#define NH_  2048
#define NO_  256

typedef __bf16 bf16_t;
typedef __bf16 bf16x8 __attribute__((ext_vector_type(8)));
typedef float  f32x4  __attribute__((ext_vector_type(4)));

#define MFMA16(a,b,c) __builtin_amdgcn_mfma_f32_16x16x32_bf16((a),(b),(c),0,0,0)

__device__ __forceinline__ void nt_store_f(float v, float* p) {
  __builtin_nontemporal_store(v, p);
}

__global__ __launch_bounds__(256) void k_cvt(const float* __restrict__ src,
                                             bf16_t* __restrict__ dst, int n) {
  int i = blockIdx.x * 256 + threadIdx.x;
  const int stride = gridDim.x * 256;
  for (; i < n; i += stride) dst[i] = (bf16_t)src[i];
}

// Decoder tile: y[dr..+16][dc..+16] = h @ Wdec^T + b_dec, K=2048 over 16 waves.
// dr = (bid>>4)*16 is always inside row-half (bid>>7) => phase-A acquire covers it.
__device__ __forceinline__ void dec_tile(int bid, int tid,
    const bf16_t* __restrict__ hbp, const bf16_t* __restrict__ Wdec,
    const float* __restrict__ b_dec, float* __restrict__ y_out, float* Scr) {
  const int lane = tid & 63;
  const int w = tid >> 6;          // wave 0..15
  const int fl = lane & 15;
  const int kg = lane >> 4;
  const int dr = (bid >> 4) * 16;
  const int dc = (bid & 15) * 16;
  f32x4 dacc = {0.f, 0.f, 0.f, 0.f};
  #pragma unroll
  for (int i = 0; i < 4; ++i) {
    const int k = w * 128 + i * 32 + kg * 8;
    bf16x8 af = *reinterpret_cast<const bf16x8*>(hbp + (size_t)(dr + fl) * NH_ + k);
    bf16x8 bf = *reinterpret_cast<const bf16x8*>(Wdec + (size_t)(dc + fl) * NH_ + k);
    dacc = MFMA16(af, bf, dacc);
  }
  __syncthreads();                 // Scr free (prior readers done)
  #pragma unroll
  for (int j = 0; j < 4; ++j)
    Scr[w * 256 + (kg * 4 + j) * 16 + fl] = dacc[j];
  __syncthreads();
  if (tid < 256) {
    const int r = tid >> 4, c = tid & 15;
    float s = b_dec[dc + c];
    #pragma unroll
    for (int ww = 0; ww < 16; ++ww) s += Scr[ww * 256 + r * 16 + c];
    nt_store_f(s, &y_out[(size_t)(dr + r) * NO_ + (dc + c)]);
  }
}

__global__ __launch_bounds__(1024, 1) void k_prnn(
    const float* __restrict__ x,
    const float* __restrict__ dt_p, const float* __restrict__ a_p,
    const float* __restrict__ Wrec, const float* __restrict__ Wenc,
    const bf16_t* __restrict__ Wdec,
    const float* __restrict__ b_rec, const float* __restrict__ b_enc,
    const float* __restrict__ b_dec,
    bf16_t* __restrict__ hb,          // 4 ring slots [B, NH] bf16 (normal stores)
    bf16_t* __restrict__ xb,          // 2 ring slots [B, NI] bf16
    int* __restrict__ flags,          // 256 flags, 64B-strided
    float* __restrict__ out)
{
  __shared__ alignas(16) bf16x8 Wl[16 * 320];   // 80KB: 16 cols x 320 K-granules
  __shared__ alignas(16) float  Scr[4096];      // 16KB: K-half reduce / dec scratch
  __shared__ alignas(16) bf16_t Ts[128 * 16];   // 4KB: h-tile transpose

  const int tid  = threadIdx.x;
  const int lane = tid & 63;
  const int fl   = lane & 15;
  const int kg   = lane >> 4;
  const int w    = tid >> 6;       // wave 0..15
  const int rt   = w & 7;          // row tile (16 rows)
  const int kh   = w >> 3;         // K half
  const int bid  = blockIdx.x;
  const int ch   = bid >> 7;       // row half
  const int cg   = bid & 127;      // col group (16 cols)
  const int rbase = ch * 128;

  const float sgate = 1.f / (1.f + expf(-dt_p[0]));
  const float av = a_p[0];
  const float gi = 1.f - sgate;
  const float sav = sgate * av;
  const int col_g = cg * 16 + fl;
  const float bias = b_rec[col_g] + b_enc[col_g];

  // f32 master state (kh==0 waves): hr[j] = h[rbase + rt*16 + kg*4 + j][col_g]
  f32x4 hr = {0.f, 0.f, 0.f, 0.f};

  // ---- prologue: W slice -> LDS (16 cols x 2560 composite K), bf16, swizzled
  {
    const int c = tid >> 6;         // local col 0..15
    const int part = tid & 63;
    const int c_g = cg * 16 + c;
    #pragma unroll
    for (int i = 0; i < 5; ++i) {
      const int g = part * 5 + i;   // granule 0..319
      const int k = g * 8;
      const float* src = (k < NH_) ? (Wrec + (size_t)c_g * NH_ + k)
                                   : (Wenc + (size_t)c_g * NI_ + (k - NH_));
      float4 f0 = reinterpret_cast<const float4*>(src)[0];
      float4 f1 = reinterpret_cast<const float4*>(src)[1];
      bf16x8 w8 = {(bf16_t)f0.x, (bf16_t)f0.y, (bf16_t)f0.z, (bf16_t)f0.w,
                   (bf16_t)f1.x, (bf16_t)f1.y, (bf16_t)f1.z, (bf16_t)f1.w};
      Wl[c * 320 + (g ^ (c & 7))] = w8;
    }
  }
  // ---- prologue: convert own share of x_0 (rows of half, cols cg*4..+4)
  if (tid < 256) {
    const int r = tid & 127, cp = tid >> 7;
    const float* xs = x + ((size_t)(rbase + r) * T_ + 0) * NI_ + cg * 4 + cp * 2;
    union { unsigned u; bf16_t h2[2]; } pk;
    pk.h2[0] = (bf16_t)xs[0]; pk.h2[1] = (bf16_t)xs[1];
    *reinterpret_cast<unsigned*>(xb + (size_t)(rbase + r) * NI_ + cg * 4 + cp * 2) = pk.u;
  }
  __syncthreads();                  // drain stores + Wl visible
  if (tid == 0)
    __hip_atomic_fetch_add(flags + bid * 16, 1, __ATOMIC_RELEASE, __HIP_MEMORY_SCOPE_AGENT);

  #pragma unroll 1
  for (int t = 0; t < T_; ++t) {
    const bf16_t* hb_in  = hb + (size_t)(t & 3) * B_ * NH_;
    bf16_t*       hb_out = hb + (size_t)((t + 1) & 3) * B_ * NH_;
    const bf16_t* xb_in  = xb + (size_t)(t & 1) * B_ * NI_;

    // ---- phase A: poll my half's 128 flags >= t+1 (paced), one acquire-inv
    if (tid < 128) {
      int* p = flags + (ch * 128 + tid) * 16;
      while (__hip_atomic_load(p, __ATOMIC_RELAXED, __HIP_MEMORY_SCOPE_AGENT) < t + 1)
        __builtin_amdgcn_s_sleep(16);
    }
    __syncthreads();
    if (tid == 0)
      (void)__hip_atomic_load(flags, __ATOMIC_ACQUIRE, __HIP_MEMORY_SCOPE_AGENT);
    __syncthreads();

    // ---- phase B: per-wave GEMM, no barriers. Wave (rt, kh): 16 rows, K-half.
    const int arow = rbase + rt * 16 + fl;
    const bf16_t* hrow = hb_in + (size_t)arow * NH_;
    const bf16_t* xrow = xb_in + (size_t)arow * NI_;
    f32x4 acc = {0.f, 0.f, 0.f, 0.f};
    #pragma unroll 8
    for (int c = 0; c < 40; ++c) {
      const int cc = kh * 40 + c;         // 32-K chunk 0..79
      const int k = cc * 32 + kg * 8;
      const bf16_t* ap = (k < NH_) ? (hrow + k) : (xrow + (k - NH_));
      bf16x8 a = *reinterpret_cast<const bf16x8*>(ap);
      bf16x8 b = Wl[fl * 320 + ((cc * 4 + kg) ^ (fl & 7))];
      acc = MFMA16(a, b, acc);
    }

    // ---- phase C: 2-way K reduce via LDS, gate in-register, transpose to Ts
    if (kh == 1) {
      #pragma unroll
      for (int j = 0; j < 4; ++j)
        Scr[rt * 256 + (kg * 4 + j) * 16 + fl] = acc[j];
    }
    __syncthreads();
    if (kh == 0) {
      #pragma unroll
      for (int j = 0; j < 4; ++j) {
        const float v = acc[j] + Scr[rt * 256 + (kg * 4 + j) * 16 + fl];
        const float o = gi * hr[j] + sav * tanhf(v + bias);
        hr[j] = o;
        Ts[(rt * 16 + kg * 4 + j) * 16 + fl] = (bf16_t)o;
        if (t == T_ - 1)    // exact f32 final h from register master
          nt_store_f(o, out + (size_t)T_ * B_ * NO_ +
                        (size_t)(rbase + rt * 16 + kg * 4 + j) * NH_ + col_g);
      }
    }
    __syncthreads();

    // ---- phase D: coalesced h write (4KB) + x_{t+1} convert, drain, release
    {
      const int r = tid >> 3, q = tid & 7;
      *reinterpret_cast<unsigned*>(hb_out + (size_t)(rbase + r) * NH_ + cg * 16 + q * 2) =
          *reinterpret_cast<const unsigned*>(&Ts[r * 16 + q * 2]);
    }
    if (t + 1 < T_ && tid < 256) {
      const int r = tid & 127, cp = tid >> 7;
      const float* xs = x + ((size_t)(rbase + r) * T_ + (t + 1)) * NI_ + cg * 4 + cp * 2;
      union { unsigned u; bf16_t h2[2]; } pk;
      pk.h2[0] = (bf16_t)xs[0]; pk.h2[1] = (bf16_t)xs[1];
      *reinterpret_cast<unsigned*>(xb + (size_t)((t + 1) & 1) * B_ * NI_ +
                                   (size_t)(rbase + r) * NI_ + cg * 4 + cp * 2) = pk.u;
    }
    __syncthreads();                // drain all global stores (vmcnt 0)
    if (tid == 0)
      __hip_atomic_fetch_add(flags + bid * 16, 1, __ATOMIC_RELEASE, __HIP_MEMORY_SCOPE_AGENT);

    // ---- phase E (off critical path): decoder y_{t-2} from slot (t-1)&3.
    // Covered by phase-A acquire chain; slot reused only by combine(t+2), which
    // transitively follows my release(t+1) — 2 steps of provable slack.
    if (t >= 2)
      dec_tile(bid, tid, hb + (size_t)((t - 1) & 3) * B_ * NH_, Wdec, b_dec,
               out + (size_t)(t - 2) * B_ * NO_, Scr);
  }

  // ---- epilogue: y_{T-2} (slot (T-1)&3) and y_{T-1} (slot T&3 = 0)
  if (tid < 128) {
    int* p = flags + (ch * 128 + tid) * 16;
    while (__hip_atomic_load(p, __ATOMIC_RELAXED, __HIP_MEMORY_SCOPE_AGENT) < T_ + 1)
      __builtin_amdgcn_s_sleep(16);
  }
  __syncthreads();
  if (tid == 0)
    (void)__hip_atomic_load(flags, __ATOMIC_ACQUIRE, __HIP_MEMORY_SCOPE_AGENT);
  __syncthreads();
  dec_tile(bid, tid, hb + (size_t)((T_ - 1) & 3) * B_ * NH_, Wdec, b_dec,
           out + (size_t)(T_ - 2) * B_ * NO_, Scr);
  dec_tile(bid, tid, hb /* slot 0 = S_{T-1} */, Wdec, b_dec,
           out + (size_t)(T_ - 1) * B_ * NO_, Scr);
}

extern "C" void kernel_launch(void* const* d_in, const int* in_sizes, int n_in,
                              void* d_out, int out_size, void* d_ws, size_t ws_size,
                              hipStream_t stream) {
  const float* x     = (const float*)d_in[0];
  const float* dt_p  = (const float*)d_in[1];
  const float* a_p   = (const float*)d_in[2];
  const float* W_enc = (const float*)d_in[3];
  const float* b_enc = (const float*)d_in[4];
  const float* W_rec = (const float*)d_in[5];
  const float* b_rec = (const float*)d_in[6];
  const float* W_dec = (const float*)d_in[7];
  const float* b_dec = (const float*)d_in[8];
  float* out = (float*)d_out;

  char* p = (char*)d_ws;
  bf16_t* hb     = (bf16_t*)p;  p += 4 * (size_t)B_ * NH_ * 2;   // 4MB (ring of 4)
  bf16_t* xb     = (bf16_t*)p;  p += 2 * (size_t)B_ * NI_ * 2;   // 512KB (ring of 2)
  bf16_t* Wdec_b = (bf16_t*)p;  p += (size_t)NO_ * NH_ * 2;      // 1MB
  int*    flags  = (int*)p;     p += 256 * 16 * 4;               // 16KB  (~5.5MB total)

  hipMemsetAsync(hb, 0, (size_t)B_ * NH_ * 2, stream);   // slot 0 = S_{-1} = 0
  hipMemsetAsync(flags, 0, 256 * 16 * 4, stream);

  k_cvt<<<64, 256, 0, stream>>>(W_dec, Wdec_b, NO_ * NH_);

  k_prnn<<<dim3(256), dim3(1024), 0, stream>>>(
      x, dt_p, a_p, W_rec, W_enc, Wdec_b, b_rec, b_enc, b_dec,
      hb, xb, flags, out);
}